// Round 7
// baseline (97.459 us; speedup 1.0000x reference)
//
#include <hip/hip_runtime.h>
#include <math.h>

#define NBOX 4096
#define ROWS 8                          // i-rows per block
#define CHUNK 256                       // j-columns per LDS chunk
#define NCHUNK (NBOX / CHUNK)           // 16
#define NBLK (NBOX / ROWS)              // 512 blocks, 256 threads each
#define SS 12                           // struct stride in floats (48 B)

typedef float v2f __attribute__((ext_vector_type(2)));
typedef float vf4 __attribute__((ext_vector_type(4)));

// Box struct (10 used floats): A0=(a0x,a1x) A1=(a0y,a1y) SC=(sc0,sc1)
// LL=(w*w,h*h) cx,cy — packed for v_pk_fma_f32.

struct Box {
    v2f A0, A1, SC, LL;
    float cx, cy;
};

__device__ __forceinline__ float rcp_fast(float x) { return __builtin_amdgcn_rcpf(x); }
__device__ __forceinline__ v2f splat(float s) { return (v2f){s, s}; }
__device__ __forceinline__ v2f fma2(v2f a, v2f b, v2f c) { return __builtin_elementwise_fma(a, b, c); }
__device__ __forceinline__ v2f abs2(v2f a) { return __builtin_elementwise_abs(a); }
__device__ __forceinline__ v2f min2(v2f a, v2f b) { return __builtin_elementwise_min(a, b); }

// Exact identities: overlap r = min(H1, H2, (H1+H2)/2 - |D|)  (signed)
//                   giou1d  g = r / (S - r),  S = H1 + H2 > 0,  r <= S/2
// Single-division tail: m_i = r_i * P / S_i with P = S0*S1*S2*S3.
// x/(P-x) is increasing, so min_i g_i = m*/(P - m*) with m* = min_i m_i.
// r <= S/2 => P - m* >= P/2 (no cancellation); P <= ~243^4 = 3.5e9 (f32 ok).
// (Validated R4-R6: absmax 0.0039 unchanged, passed.)
__device__ __forceinline__ float mgiou_pair(const Box& I, const Box& J) {
    v2f dA = fma2(I.A0, splat(J.A0.x), I.A1 * J.A1.x);   // (u0.v0, u1.v0)
    v2f dB = fma2(I.A0, splat(J.A0.y), I.A1 * J.A1.y);   // (u0.v1, u1.v1)
    v2f DI = fma2(I.A0, splat(J.cx), fma2(I.A1, splat(J.cy), -I.SC));
    v2f DJ = fma2(J.A0, splat(I.cx), fma2(J.A1, splat(I.cy), -J.SC));
    v2f aA = abs2(dA), aB = abs2(dB);
    v2f HI = aA + aB;                                   // J extents on I axes
    v2f HJ = (v2f){aA.x, aB.x} + (v2f){aA.y, aB.y};     // I extents on J axes
    v2f SI = I.LL + HI;
    v2f SJ = J.LL + HJ;
    v2f uI = fma2(splat(0.5f), SI, -abs2(DI));
    v2f uJ = fma2(splat(0.5f), SJ, -abs2(DJ));
    v2f rI = min2(min2(I.LL, HI), uI);
    v2f rJ = min2(min2(J.LL, HJ), uJ);
    float S01 = SI.x * SI.y, S23 = SJ.x * SJ.y;
    float P = S01 * S23;
    v2f mI = rI * (v2f){SI.y, SI.x} * splat(S23);
    v2f mJ = rJ * (v2f){SJ.y, SJ.x} * splat(S01);
    float mm = fminf(fminf(mI.x, mI.y), fminf(mJ.x, mJ.y));
    return fmaxf(mm, 0.0f) * rcp_fast(P - mm);
}

// Cumulative swizzle (+4 floats per 8-struct octet). For lane-quad reads
// (structs 4l..4l+3), each 8-lane group's b128 bases mod 32 are
// {0,16,4,20,8,24,12,28} (+coset) — every bank covered exactly once per
// 8 lanes -> exactly the 8-cycle wave64-b128 floor, zero conflicts.
__device__ __forceinline__ int sw_offset(int i) { return i * SS + (i >> 3) * 4; }

__device__ __forceinline__ Box load_box(const float* p) {
    Box b;
    float4 x = *(const float4*)(p);
    float4 y = *(const float4*)(p + 4);
    float2 z = *(const float2*)(p + 8);
    b.A0 = (v2f){x.x, x.y}; b.A1 = (v2f){x.z, x.w};
    b.SC = (v2f){y.x, y.y}; b.LL = (v2f){y.z, y.w};
    b.cx = z.x; b.cy = z.y;
    return b;
}

__device__ __forceinline__ Box make_box(const float* __restrict__ boxes, int box) {
    float cx = boxes[box * 5 + 0];
    float cy = boxes[box * 5 + 1];
    float w  = boxes[box * 5 + 2];
    float h  = boxes[box * 5 + 3];
    float ang = boxes[box * 5 + 4];
    float s, c;
    __sincosf(ang, &s, &c);
    float a0x = w * c, a0y = -w * s;        // full edge vectors (match ref rot)
    float a1x = h * s, a1y =  h * c;
    Box b;
    b.A0 = (v2f){a0x, a1x};
    b.A1 = (v2f){a0y, a1y};
    b.SC = (v2f){fmaf(a0x, cx, a0y * cy), fmaf(a1x, cx, a1y * cy)};
    b.LL = (v2f){w * w, h * h};
    b.cx = cx; b.cy = cy;
    return b;
}

// R19->R20 (scatter discriminator): all scheduling/occupancy/L2 theories
// falsified; surviving theory is a DRAM write-scatter ceiling (~3.4 TB/s
// observed in R4's 156MB spill run vs 5.97 fill) from 128B chunks scattered
// over thousands of 16KiB-strided rows. This kernel: 512 row-panel blocks,
// each owns 8 FULL output rows written strictly left-to-right in 1 KiB
// contiguous wave-bursts (16 sequential bursts/row, row-buffer friendly).
// Price: 2x compute (full matrix, no mirror). Predict: scatter theory ->
// dur 70-76; falsified -> 80-84 and the 23us kernel is the write floor.
__global__ __launch_bounds__(256)
void pairwise_kernel(const float* __restrict__ boxes, float* __restrict__ out) {
    __shared__ float sm[CHUNK * SS + (CHUNK / 8) * 4];   // 3200 floats

    int tid = threadIdx.x;
    int wave = tid >> 6;        // 0..3: rows 2*wave, 2*wave+1 of the panel
    int lane = tid & 63;

    int i0 = blockIdx.x * ROWS + 2 * wave;
    Box I0 = make_box(boxes, i0);
    Box I1 = make_box(boxes, i0 + 1);

    for (int c = 0; c < NCHUNK; ++c) {
        __syncthreads();        // previous chunk's reads complete
        {   // stage: thread tid builds struct for box c*CHUNK + tid
            int box = c * CHUNK + tid;
            Box b = make_box(boxes, box);
            float* d = &sm[sw_offset(tid)];
            ((float4*)d)[0] = make_float4(b.A0.x, b.A0.y, b.A1.x, b.A1.y);
            ((float4*)d)[1] = make_float4(b.SC.x, b.SC.y, b.LL.x, b.LL.y);
            ((float2*)d)[4] = make_float2(b.cx, b.cy);
        }
        __syncthreads();

        // lane covers columns jg0..jg0+3 of this chunk
        int jg0 = c * CHUNK + 4 * lane;
        Box J0 = load_box(&sm[sw_offset(4 * lane + 0)]);
        Box J1 = load_box(&sm[sw_offset(4 * lane + 1)]);
        Box J2 = load_box(&sm[sw_offset(4 * lane + 2)]);
        Box J3 = load_box(&sm[sw_offset(4 * lane + 3)]);

        float a0 = (i0     == jg0 + 0) ? 0.0f : mgiou_pair(I0, J0);
        float a1 = (i0     == jg0 + 1) ? 0.0f : mgiou_pair(I0, J1);
        float a2 = (i0     == jg0 + 2) ? 0.0f : mgiou_pair(I0, J2);
        float a3 = (i0     == jg0 + 3) ? 0.0f : mgiou_pair(I0, J3);
        vf4 oa = {a0, a1, a2, a3};
        *(vf4*)&out[(size_t)i0 * NBOX + jg0] = oa;      // 64 lanes x 16B = 1 KiB seq

        float b0 = (i0 + 1 == jg0 + 0) ? 0.0f : mgiou_pair(I1, J0);
        float b1 = (i0 + 1 == jg0 + 1) ? 0.0f : mgiou_pair(I1, J1);
        float b2 = (i0 + 1 == jg0 + 2) ? 0.0f : mgiou_pair(I1, J2);
        float b3 = (i0 + 1 == jg0 + 3) ? 0.0f : mgiou_pair(I1, J3);
        vf4 ob = {b0, b1, b2, b3};
        *(vf4*)&out[(size_t)(i0 + 1) * NBOX + jg0] = ob;
    }
}

extern "C" void kernel_launch(void* const* d_in, const int* in_sizes, int n_in,
                              void* d_out, int out_size, void* d_ws, size_t ws_size,
                              hipStream_t stream) {
    const float* boxes = (const float*)d_in[0];
    float* out = (float*)d_out;
    pairwise_kernel<<<dim3(NBLK), dim3(256), 0, stream>>>(boxes, out);
}

// Round 8
// 91.727 us; speedup vs baseline: 1.0625x; 1.0625x over previous
//
#include <hip/hip_runtime.h>
#include <math.h>

#define NBOX 4096
#define TILE 32
#define NT (NBOX / TILE)               // 128
#define NBLK (NT * (NT + 1) / 2)       // 8256 upper-triangle tiles, 1 wave each
#define SS 12                          // I-struct stride in floats (48 B)
#define JB 400                         // J region base (I region = 396, padded)
#define JPS 20                         // J pair-block stride in floats (80 B, 16B-aligned)

typedef float v2f __attribute__((ext_vector_type(2)));
typedef float vf4 __attribute__((ext_vector_type(4)));

__device__ __forceinline__ float rcp_fast(float x) { return __builtin_amdgcn_rcpf(x); }
__device__ __forceinline__ v2f splat(float s) { return (v2f){s, s}; }
__device__ __forceinline__ v2f fma2(v2f a, v2f b, v2f c) { return __builtin_elementwise_fma(a, b, c); }
__device__ __forceinline__ v2f abs2(v2f a) { return __builtin_elementwise_abs(a); }
__device__ __forceinline__ v2f min2(v2f a, v2f b) { return __builtin_elementwise_min(a, b); }
__device__ __forceinline__ v2f max2(v2f a, v2f b) { return __builtin_elementwise_max(a, b); }

// I-side box, scalar (lane-uniform across the packed pair)
struct IBox { float a0x, a1x, a0y, a1y, sc0, sc1, l0, l1, cx, cy; };
// J-side box pair, packed across two boxes (slot 0 = J0, slot 1 = J1)
struct PJ { v2f a0x, a1x, a0y, a1y, sc0, sc1, l0, l1, cx, cy; };

// Exact identities (validated R4-R7, absmax 0.0039):
//   overlap r = min(H1, H2, (H1+H2)/2 - |D|)  (signed);  g = r/(S-r)
//   single-division tail: m_i = r_i*P/S_i, P=S0*S1*S2*S3; min_i g_i = m*/(P-m*)
// R8: packed ACROSS THE PAIR AXIS — every op below is slot-parallel (VOP3P
// v_pk_* eligible), zero cross-slot swizzles. 2 pairs per call, 2 scalar rcps.
__device__ __forceinline__ v2f mgiou_pair2(const IBox& I, const PJ& J) {
    v2f d00 = fma2(splat(I.a0y), J.a0y, splat(I.a0x) * J.a0x);   // u0.v0
    v2f d01 = fma2(splat(I.a0y), J.a1y, splat(I.a0x) * J.a1x);   // u0.v1
    v2f d10 = fma2(splat(I.a1y), J.a0y, splat(I.a1x) * J.a0x);   // u1.v0
    v2f d11 = fma2(splat(I.a1y), J.a1y, splat(I.a1x) * J.a1x);   // u1.v1
    v2f DI0 = fma2(splat(I.a0x), J.cx, fma2(splat(I.a0y), J.cy, splat(-I.sc0)));
    v2f DI1 = fma2(splat(I.a1x), J.cx, fma2(splat(I.a1y), J.cy, splat(-I.sc1)));
    v2f DJ0 = fma2(J.a0x, splat(I.cx), fma2(J.a0y, splat(I.cy), -J.sc0));
    v2f DJ1 = fma2(J.a1x, splat(I.cx), fma2(J.a1y, splat(I.cy), -J.sc1));
    v2f a00 = abs2(d00), a01 = abs2(d01), a10 = abs2(d10), a11 = abs2(d11);
    v2f HI0 = a00 + a01, HI1 = a10 + a11;       // J extent on I axes
    v2f HJ0 = a00 + a10, HJ1 = a01 + a11;       // I extent on J axes
    v2f SI0 = splat(I.l0) + HI0, SI1 = splat(I.l1) + HI1;
    v2f SJ0 = J.l0 + HJ0, SJ1 = J.l1 + HJ1;
    v2f uI0 = fma2(splat(0.5f), SI0, -abs2(DI0));
    v2f uI1 = fma2(splat(0.5f), SI1, -abs2(DI1));
    v2f uJ0 = fma2(splat(0.5f), SJ0, -abs2(DJ0));
    v2f uJ1 = fma2(splat(0.5f), SJ1, -abs2(DJ1));
    v2f rI0 = min2(min2(splat(I.l0), HI0), uI0);
    v2f rI1 = min2(min2(splat(I.l1), HI1), uI1);
    v2f rJ0 = min2(min2(J.l0, HJ0), uJ0);
    v2f rJ1 = min2(min2(J.l1, HJ1), uJ1);
    v2f S01 = SI0 * SI1, S23 = SJ0 * SJ1;
    v2f P = S01 * S23;
    v2f mI0 = rI0 * SI1 * S23;
    v2f mI1 = rI1 * SI0 * S23;
    v2f mJ0 = rJ0 * SJ1 * S01;
    v2f mJ1 = rJ1 * SJ0 * S01;
    v2f mm = min2(min2(mI0, mI1), min2(mJ0, mJ1));
    mm = max2(mm, splat(0.0f));
    v2f den = P - mm;
    v2f r = {rcp_fast(den.x), rcp_fast(den.y)};
    return mm * r;
}

// I-region cumulative swizzle (verified conflict-free in the 81.0us baseline)
__device__ __forceinline__ int sw_offset(int i) { return i * SS + (i >> 3) * 4; }

__device__ __forceinline__ IBox load_ibox(const float* p) {
    float4 x = *(const float4*)(p);
    float4 y = *(const float4*)(p + 4);
    float2 z = *(const float2*)(p + 8);
    IBox b;
    b.a0x = x.x; b.a1x = x.y; b.a0y = x.z; b.a1y = x.w;
    b.sc0 = y.x; b.sc1 = y.y; b.l0 = y.z; b.l1 = y.w;
    b.cx = z.x; b.cy = z.y;
    return b;
}

// J pair-block p base: JB + 20p floats (80B, 16B-aligned). b128 bases mod 32
// across tx-lanes: 20p mod 32 in {0,8,16,24} twice -> 2 addrs per bank-group
// = 2-way = free (m136); 8 ty-lanes broadcast per address.
__device__ __forceinline__ PJ load_pj(const float* p) {
    float4 q0 = *(const float4*)(p);
    float4 q1 = *(const float4*)(p + 4);
    float4 q2 = *(const float4*)(p + 8);
    float4 q3 = *(const float4*)(p + 12);
    float4 q4 = *(const float4*)(p + 16);
    PJ j;
    j.a0x = (v2f){q0.x, q0.y}; j.a1x = (v2f){q0.z, q0.w};
    j.a0y = (v2f){q1.x, q1.y}; j.a1y = (v2f){q1.z, q1.w};
    j.sc0 = (v2f){q2.x, q2.y}; j.sc1 = (v2f){q2.z, q2.w};
    j.l0  = (v2f){q3.x, q3.y}; j.l1  = (v2f){q3.z, q3.w};
    j.cx  = (v2f){q4.x, q4.y}; j.cy  = (v2f){q4.z, q4.w};
    return j;
}

// R20->R21: R7 proved compute-bound (kernel 23us = 16.7 compute + ~6 other;
// write theories all dead). Suspect: component-axis v2f packing forced
// scalarization + swizzle moves. This round: PAIR-AXIS packing — all math
// slot-parallel v_pk_* with zero swizzles; J staged in pair-SoA LDS. R0
// structure otherwise frozen. Predict: issue-bound -> 75-77; stall-bound ->
// neutral 81 (then attack latency); codegen regression -> 83-85.
__global__ __launch_bounds__(64)
void pairwise_kernel(const float* __restrict__ boxes, float* __restrict__ out) {
    // decode (bi, bj), bi <= bj, row-major over the upper triangle
    int k = blockIdx.x;
    int bi = (int)((float)(2 * NT + 1 - sqrtf((float)((2 * NT + 1) * (2 * NT + 1) - 8 * k))) * 0.5f);
    if (bi > 0 && k < bi * NT - bi * (bi - 1) / 2) bi--;
    if (k >= (bi + 1) * NT - (bi + 1) * bi / 2) bi++;
    int bj = bi + (k - (bi * NT - bi * (bi - 1) / 2));

    __shared__ float sm[JB + 16 * JPS];     // I AoS @0, J pair-SoA @JB

    int tid = threadIdx.x;
    {   // fused precompute: 64 threads each build one box struct
        int loc = tid & (TILE - 1);
        int box = ((tid < TILE) ? bi : bj) * TILE + loc;
        float cx = boxes[box * 5 + 0];
        float cy = boxes[box * 5 + 1];
        float w  = boxes[box * 5 + 2];
        float h  = boxes[box * 5 + 3];
        float ang = boxes[box * 5 + 4];
        float s, c;
        __sincosf(ang, &s, &c);
        float a0x = w * c, a0y = -w * s;    // full edge vectors (match ref rot)
        float a1x = h * s, a1y =  h * c;
        float sc0 = fmaf(a0x, cx, a0y * cy);
        float sc1 = fmaf(a1x, cx, a1y * cy);
        if (tid < TILE) {
            float* d = &sm[sw_offset(loc)];
            ((float4*)d)[0] = make_float4(a0x, a1x, a0y, a1y);
            ((float4*)d)[1] = make_float4(sc0, sc1, w * w, h * h);
            ((float2*)d)[4] = make_float2(cx, cy);
        } else {
            // pair-SoA: element e of box-pair (p, s): JB + 20p + 2e + s.
            // Banks (20p+2e+s) mod 32: 16 p-values x 2 s -> each bank 2 lanes
            // = 2-way = free.
            int p = loc >> 1, s2 = loc & 1;
            float* d = &sm[JB + JPS * p + s2];
            d[0]  = a0x; d[2]  = a1x; d[4]  = a0y; d[6]  = a1y;
            d[8]  = sc0; d[10] = sc1; d[12] = w * w; d[14] = h * h;
            d[16] = cx;  d[18] = cy;
        }
    }
    __syncthreads();

    int tx = tid & 7;           // j quad: 4tx .. 4tx+3   (32 cols)
    int ty = tid >> 3;          // i quad: 4ty .. 4ty+3   (32 rows)

    // two packed J-pairs: (4tx, 4tx+1) = block 2tx, (4tx+2, 4tx+3) = block 2tx+1
    PJ PJ0 = load_pj(&sm[JB + JPS * (2 * tx)]);
    PJ PJ1 = load_pj(&sm[JB + JPS * (2 * tx + 1)]);

    int ibase = bi * TILE, jbase = bj * TILE;
    bool diag = (bi == bj);
    const float* ip = &sm[sw_offset(4 * ty)];
    float vT[4][4];             // vT[m][kk] for the mirror stores

    #pragma unroll
    for (int kk = 0; kk < 4; ++kk) {
        IBox I = load_ibox(ip + kk * SS);
        int ig = ibase + 4 * ty + kk;
        v2f g01 = mgiou_pair2(I, PJ0);
        v2f g23 = mgiou_pair2(I, PJ1);
        if (diag) {             // uniform branch; 128 of 8256 blocks
            int jg0 = jbase + 4 * tx;
            if (ig == jg0)     g01.x = 0.0f;
            if (ig == jg0 + 1) g01.y = 0.0f;
            if (ig == jg0 + 2) g23.x = 0.0f;
            if (ig == jg0 + 3) g23.y = 0.0f;
        }
        vT[0][kk] = g01.x; vT[1][kk] = g01.y;
        vT[2][kk] = g23.x; vT[3][kk] = g23.y;
        // upper tile: per instr, 8 i-rows x (8 lanes x 16 B = 128 B contiguous)
        vf4 o = {g01.x, g01.y, g23.x, g23.y};
        *(vf4*)&out[(size_t)ig * NBOX + jbase + 4 * tx] = o;
    }

    if (!diag) {
        // mirror tile: per instr, 8 j-rows x (8 ty-lanes x 16 B = 128 B contiguous)
        #pragma unroll
        for (int m = 0; m < 4; ++m) {
            int jg = jbase + 4 * tx + m;
            vf4 o = {vT[m][0], vT[m][1], vT[m][2], vT[m][3]};
            *(vf4*)&out[(size_t)jg * NBOX + ibase + 4 * ty] = o;
        }
    }
}

extern "C" void kernel_launch(void* const* d_in, const int* in_sizes, int n_in,
                              void* d_out, int out_size, void* d_ws, size_t ws_size,
                              hipStream_t stream) {
    const float* boxes = (const float*)d_in[0];
    float* out = (float*)d_out;
    pairwise_kernel<<<dim3(NBLK), dim3(64), 0, stream>>>(boxes, out);
}